// Round 8
// baseline (276.391 us; speedup 1.0000x reference)
//
#include <hip/hip_runtime.h>
#include <stdint.h>

#define BATCH 128
#define NN 512
#define BINS 100
#define WORDS 8    // 512 bits / 64; natural order: bit b of word m = column 64m+b
#define WPAD 9     // +1 u64 pad -> benign LDS bank aliasing
#define ECAP 6144  // upper-tri edge capacity; expected ~2615, huge margin

// spread 16 bits to stride-4 positions (bit i -> bit 4i)
__device__ __forceinline__ unsigned long long spread4(unsigned long long x) {
    x = (x | (x << 24)) & 0x000000ff000000ffull;
    x = (x | (x << 12)) & 0x000f000f000f000full;
    x = (x | (x <<  6)) & 0x0303030303030303ull;
    x = (x | (x <<  3)) & 0x1111111111111111ull;
    return x;
}

// R13 (2nd submit; round 7 hit GPUAcquisitionTimeout, never ran):
// footprint-DENSITY experiment. Three scheduling theories for the
// ~2.6TB/s phase-1 pin are dead (R10 wave-parallel, R11 MLP unroll, R12
// channel-phase rot). All variants ever tried shared the same gappy
// masked-triangle footprint. Now: top half (r<256) reads FULL 2KB rows
// (sub-diagonal floats are true values by symmetry -> rows arrive complete);
// bottom half reads the full upper 1KB (words 4..7 complete incl.
// sub-diagonal words). Every load is a full-wave unmasked contiguous 1KB;
// block's top-half aggregate is a perfect 512KB sequential stream. Traffic
// 151->196MB (+30%) traded for density. Phase 1b collapses to 16 fixed
// transposes (words 0..3 of bottom rows), no diagonal completion, no
// pair-index math. Fused last-block MMD kept (one fewer launch than R9).
__global__ __launch_bounds__(1024) void k_cluster_hist(
    const float* __restrict__ adj1, const float* __restrict__ adj2,
    float* __restrict__ hist /* [2*BATCH][BINS] */,
    unsigned int* __restrict__ mmd_cnt)
{
    __shared__ unsigned long long bits[NN][WPAD];   // 36,864 B
    __shared__ unsigned int edges[ECAP];            // 24,576 B
    __shared__ int tri2[NN];                        //  2,048 B
    __shared__ int histI[BINS];
    __shared__ int ecnt;

    const int gb = blockIdx.x;  // 0..255
    const float* __restrict__ gp =
        (gb < BATCH ? adj1 : adj2) + (size_t)(gb & (BATCH - 1)) * NN * NN;

    const int tid  = threadIdx.x;
    const int lane = tid & 63;
    const int wave = tid >> 6;  // 0..15

    if (tid < BINS) histI[tid] = 0;
    if (tid < NN)   tri2[tid]  = 0;
    if (tid == 0)   ecnt = 0;
    if (gb == 0 && tid == 0) *mmd_cnt = 0;  // arm the fused-MMD last-block flag

    // ---- Phase 1 (top half, k=0..15 -> r<256): dense full-row read.
    // Sub-diagonal values are true data (A symmetric, zero diag) -> the row's
    // 8 words are COMPLETE, no masking, no later completion.
    for (int k = 0; k < 16; ++k) {
        const int r = wave + (k << 4);  // < 256
        const float* rp = gp + (size_t)r * NN;
        float4 v0 = *(const float4*)(rp + 4 * lane);          // cols 0..255
        float4 v1 = *(const float4*)(rp + 256 + 4 * lane);    // cols 256..511
        unsigned long long a0 = __ballot(v0.x != 0.0f);
        unsigned long long a1 = __ballot(v0.y != 0.0f);
        unsigned long long a2 = __ballot(v0.z != 0.0f);
        unsigned long long a3 = __ballot(v0.w != 0.0f);
        unsigned long long c0 = __ballot(v1.x != 0.0f);
        unsigned long long c1 = __ballot(v1.y != 0.0f);
        unsigned long long c2 = __ballot(v1.z != 0.0f);
        unsigned long long c3 = __ballot(v1.w != 0.0f);
        if (lane < 8) {
            const int d  = lane;
            const int sh = 16 * (d & 3);
            unsigned long long w;
            if (d < 4)
                w = (spread4((a0 >> sh) & 0xFFFFull) << 0) |
                    (spread4((a1 >> sh) & 0xFFFFull) << 1) |
                    (spread4((a2 >> sh) & 0xFFFFull) << 2) |
                    (spread4((a3 >> sh) & 0xFFFFull) << 3);
            else
                w = (spread4((c0 >> sh) & 0xFFFFull) << 0) |
                    (spread4((c1 >> sh) & 0xFFFFull) << 1) |
                    (spread4((c2 >> sh) & 0xFFFFull) << 2) |
                    (spread4((c3 >> sh) & 0xFFFFull) << 3);
            bits[r][d] = w;
        }
    }
    // ---- Phase 1 (bottom half, k=16..31 -> r>=256): full upper-1KB read.
    // Words 4..7 complete (incl. sub-diagonal words: true data by symmetry).
    for (int k = 16; k < 32; ++k) {
        const int r = wave + (k << 4);  // >= 256
        const float* rp = gp + (size_t)r * NN;
        float4 v1 = *(const float4*)(rp + 256 + 4 * lane);    // cols 256..511
        unsigned long long c0 = __ballot(v1.x != 0.0f);
        unsigned long long c1 = __ballot(v1.y != 0.0f);
        unsigned long long c2 = __ballot(v1.z != 0.0f);
        unsigned long long c3 = __ballot(v1.w != 0.0f);
        if (lane < 4) {
            const int sh = 16 * lane;
            unsigned long long w =
                (spread4((c0 >> sh) & 0xFFFFull) << 0) |
                (spread4((c1 >> sh) & 0xFFFFull) << 1) |
                (spread4((c2 >> sh) & 0xFFFFull) << 2) |
                (spread4((c3 >> sh) & 0xFFFFull) << 3);
            bits[r][4 + lane] = w;
        }
    }
    __syncthreads();

    // ---- Phase 1b: fill words 0..3 of bottom rows: 16 fixed 64x64 bit
    // transposes, one per wave. bi = 4+(wave>>2) (row block), bj = wave&3
    // (word). Source: upper block (bj, bi), complete from the dense top half.
    {
        const int bi = 4 + (wave >> 2);
        const int bj = wave & 3;
        unsigned long long t = bits[(bj << 6) + lane][bi];
        const unsigned long long M[6] = {
            0x5555555555555555ull, 0x3333333333333333ull,
            0x0f0f0f0f0f0f0f0full, 0x00ff00ff00ff00ffull,
            0x0000ffff0000ffffull, 0x00000000ffffffffull };
        #pragma unroll
        for (int s = 0; s < 6; ++s) {
            const int k = 1 << s;
            unsigned long long y = __shfl_xor((long long)t, k, 64);
            if ((lane & k) == 0) t = (t &  M[s]) | ((y &  M[s]) << k);
            else                 t = (t & ~M[s]) | ((y & ~M[s]) >> k);
        }
        bits[(bi << 6) + lane][bj] = t;
    }
    __syncthreads();

    // ---- Phase 2a: upper-tri edge list (j > r); j = 64m + L.
    for (int p = tid; p < NN * WORDS; p += 1024) {
        int r = p >> 3;
        int m = p & 7;
        unsigned long long w = bits[r][m];
        int base = m << 6;
        int sh = r - base + 1;  // keep bits L with base+L > r
        unsigned long long wm =
            (sh <= 0) ? w : (sh >= 64 ? 0ull : (w & (~0ull << sh)));
        int cnt = __popcll(wm);

        int x = cnt;
        #pragma unroll
        for (int off = 1; off < 64; off <<= 1) {
            int y = __shfl_up(x, off, 64);
            if (lane >= off) x += y;
        }
        int excl = x - cnt;
        int bs = 0;
        if (lane == 63) bs = atomicAdd(&ecnt, x);
        bs = __shfl(bs, 63, 64);

        int idx = bs + excl;
        while (wm) {
            int L = __builtin_ctzll(wm);
            wm &= wm - 1;
            int j = base + L;
            if (idx < ECAP) edges[idx] = ((unsigned)r << 10) | (unsigned)j;
            ++idx;
        }
    }
    __syncthreads();

    // ---- Phase 2b: edge-parallel intersection counts.
    const int ne = ecnt < ECAP ? ecnt : ECAP;
    for (int e = tid; e < ne; e += 1024) {
        unsigned ed = edges[e];
        int i = ed >> 10;
        int j = ed & 1023;
        int acc = 0;
        #pragma unroll
        for (int w = 0; w < WORDS; ++w)
            acc += __popcll(bits[i][w] & bits[j][w]);
        atomicAdd(&tri2[i], acc);
        atomicAdd(&tri2[j], acc);
    }
    __syncthreads();

    // ---- Phase 2c: clustering coeff + histogram.
    if (tid < NN) {
        int deg = 0;
        #pragma unroll
        for (int w = 0; w < WORDS; ++w) deg += __popcll(bits[tid][w]);
        float t2    = (float)tri2[tid];
        float degf  = (float)deg;
        float denom = degf * (degf - 1.0f);
        float c = denom > 0.0f ? t2 / denom : 0.0f;  // exact int/int in fp32
        int idx = (int)(c * 100.0f);                  // trunc == astype(int32)
        idx = idx < 0 ? 0 : (idx > BINS - 1 ? BINS - 1 : idx);
        atomicAdd(&histI[idx], 1);
    }
    __syncthreads();

    if (tid < BINS) hist[(size_t)gb * BINS + tid] = (float)histI[tid];
}

// ---------------- fused MMD kernel (partial + last-block final) -------------
__global__ __launch_bounds__(256) void k_mmd(
    const float* __restrict__ hist, float* __restrict__ partials,
    unsigned int* __restrict__ cnt, float* __restrict__ out)
{
    int p = blockIdx.x * 256 + threadIdx.x;
    int t   = p >> 14;          // 0:XX 1:YY 2:XY
    int rem = p & 16383;
    int i = rem >> 7;
    int j = rem & 127;
    const float4* x4;
    const float4* y4;
    float w;
    if (t == 0)      { x4 = (const float4*)(hist + (size_t)i * BINS);           y4 = (const float4*)(hist + (size_t)j * BINS);           w =  1.0f; }
    else if (t == 1) { x4 = (const float4*)(hist + (size_t)(BATCH + i) * BINS); y4 = (const float4*)(hist + (size_t)(BATCH + j) * BINS); w =  1.0f; }
    else             { x4 = (const float4*)(hist + (size_t)i * BINS);           y4 = (const float4*)(hist + (size_t)(BATCH + j) * BINS); w = -2.0f; }
    float sq = 0.0f;
    #pragma unroll
    for (int k = 0; k < BINS / 4; ++k) {
        float4 a = x4[k];
        float4 b = y4[k];
        float d0 = a.x - b.x, d1 = a.y - b.y, d2 = a.z - b.z, d3 = a.w - b.w;
        sq += d0 * d0 + d1 * d1 + d2 * d2 + d3 * d3;
    }
    float local = w * expf(-0.5f * sq);  // sigma=1

    __shared__ float red[256];
    __shared__ bool amLast;
    red[threadIdx.x] = local;
    __syncthreads();
    for (int s = 128; s >= 1; s >>= 1) {
        if (threadIdx.x < s) red[threadIdx.x] += red[threadIdx.x + s];
        __syncthreads();
    }
    if (threadIdx.x == 0) {
        partials[blockIdx.x] = red[0];
        __threadfence();                        // release partial (device scope)
        amLast = (atomicAdd(cnt, 1u) == 191u);  // device-scope counter
    }
    __syncthreads();
    if (amLast) {
        __threadfence();                        // acquire others' partials
        if (threadIdx.x < 64) {
            // byte-identical reduction order to R9's k_mmd_final
            float v = 0.0f;
            for (int q = threadIdx.x; q < 192; q += 64) v += partials[q];
            #pragma unroll
            for (int off = 32; off >= 1; off >>= 1) v += __shfl_xor(v, off, 64);
            if (threadIdx.x == 0) out[0] = v * (1.0f / (float)(BATCH * BATCH));
        }
    }
}

extern "C" void kernel_launch(void* const* d_in, const int* in_sizes, int n_in,
                              void* d_out, int out_size, void* d_ws, size_t ws_size,
                              hipStream_t stream) {
    const float* a1 = (const float*)d_in[0];
    const float* a2 = (const float*)d_in[1];
    float* out = (float*)d_out;

    const size_t hist_bytes = (size_t)2 * BATCH * BINS * 4;  // 102,400 B
    float* hist            = (float*)d_ws;
    float* partials        = (float*)((char*)d_ws + hist_bytes);          // 768 B
    unsigned int* mmd_cnt  = (unsigned int*)((char*)d_ws + hist_bytes + 1024);

    hipLaunchKernelGGL(k_cluster_hist, dim3(2 * BATCH), dim3(1024), 0, stream,
                       a1, a2, hist, mmd_cnt);
    hipLaunchKernelGGL(k_mmd, dim3(192), dim3(256), 0, stream,
                       hist, partials, mmd_cnt, out);
}

// Round 11
// 256.509 us; speedup vs baseline: 1.0775x; 1.0775x over previous
//
#include <hip/hip_runtime.h>
#include <stdint.h>

#define BATCH 128
#define NN 512
#define BINS 100
#define WORDS 8    // 512 bits / 64; natural order: bit b of word m = column 64m+b
#define WPAD 9     // +1 u64 pad -> benign LDS bank aliasing
#define ECAP 6144  // upper-tri edge capacity; expected ~2615, huge margin

// spread 16 bits to stride-4 positions (bit i -> bit 4i)
__device__ __forceinline__ unsigned long long spread4(unsigned long long x) {
    x = (x | (x << 24)) & 0x000000ff000000ffull;
    x = (x | (x << 12)) & 0x000f000f000f000full;
    x = (x | (x <<  6)) & 0x0303030303030303ull;
    x = (x | (x <<  3)) & 0x1111111111111111ull;
    return x;
}

// non-temporal (no-allocate) 16B load. __builtin_nontemporal_load requires a
// native scalar/vector pointer (NOT HIP_vector_type) -> use a clang
// ext_vector float4, layout-identical to float4. Phase-1 data is read
// exactly once; L1 allocation is pure overhead and the prime suspect for the
// measured ~4 B/cyc/CU per-CU line-rate pin (constant across 7 variants).
typedef float vfloat4 __attribute__((ext_vector_type(4)));
__device__ __forceinline__ vfloat4 ld_nt(const float* p) {
    return __builtin_nontemporal_load((const vfloat4*)p);
}

// R14 (3rd submit; 1st failed to compile on HIP_vector_type, 2nd hit
// GPUAcquisitionTimeout). Cache-policy experiment on the known-best R9
// structure. R13's counters (first direct look): 88us, FETCH 98MB, HBM
// 1.14TB/s (14%), VALU 27%, conflicts ~0 -> NOT BW/VALU/LDS-bound. Time
// scales with bytes at a fixed ~2.5TB/s effective rate (= ~4B/cyc/CU line
// rate), identical across: 5 staging structures, R10 32-wave pack, R11
// 8-deep MLP, R12 address-phase rot, R13 dense stream. All scheduling
// theories dead; the remaining suspect is the per-CU L1 line-allocate path
// (same cost whether the line comes from HBM or L3 -- explains R13's
// L3-hit half not helping). So: minimal-bytes masked triangle (R9, 151MB)
// + nt phase-1 loads. Keep R11's fused last-block MMD (absmax 0 three
// times; one fewer launch).
__global__ __launch_bounds__(1024) void k_cluster_hist(
    const float* __restrict__ adj1, const float* __restrict__ adj2,
    float* __restrict__ hist /* [2*BATCH][BINS] */,
    unsigned int* __restrict__ mmd_cnt)
{
    __shared__ unsigned long long bits[NN][WPAD];   // 36,864 B
    __shared__ unsigned int edges[ECAP];            // 24,576 B
    __shared__ int tri2[NN];                        //  2,048 B
    __shared__ int histI[BINS];
    __shared__ int ecnt;

    const int gb = blockIdx.x;  // 0..255
    const float* __restrict__ gp =
        (gb < BATCH ? adj1 : adj2) + (size_t)(gb & (BATCH - 1)) * NN * NN;

    const int tid  = threadIdx.x;
    const int lane = tid & 63;
    const int wave = tid >> 6;  // 0..15

    if (tid < BINS) histI[tid] = 0;
    if (tid < NN)   tri2[tid]  = 0;
    if (tid == 0)   ecnt = 0;
    if (gb == 0 && tid == 0) *mmd_cnt = 0;  // arm the fused-MMD last-block flag

    // ---- Phase 1: upper-triangle read + natural-order pack (R9 form, nt).
    for (int r = wave; r < NN; r += 16) {
        const int br = r >> 6;       // diagonal 64-col block
        const int nb = 8 - br;       // words to read
        const int c0 = br << 6;
        const int rr = r & 63;
        // lanes 0..15 cover the diagonal word; skip lanes with all 4 cols <= r
        const int Lmin = (rr < 3) ? 0 : ((rr + 1) >> 2);
        vfloat4 v = (vfloat4)0.0f;
        if (lane < 16 * nb && (lane >= 16 || lane >= Lmin))
            v = ld_nt(gp + (size_t)r * NN + c0 + 4 * lane);
        unsigned long long b0 = __ballot(v.x != 0.0f);
        unsigned long long b1 = __ballot(v.y != 0.0f);
        unsigned long long b2 = __ballot(v.z != 0.0f);
        unsigned long long b3 = __ballot(v.w != 0.0f);
        // lane d < nb assembles natural word m = br + d from span word s = d
        if (lane < nb) {
            const int sh = 16 * lane;
            unsigned long long w =
                (spread4((b0 >> sh) & 0xFFFFull) << 0) |
                (spread4((b1 >> sh) & 0xFFFFull) << 1) |
                (spread4((b2 >> sh) & 0xFFFFull) << 2) |
                (spread4((b3 >> sh) & 0xFFFFull) << 3);
            bits[r][br + lane] = w;
        }
    }
    __syncthreads();

    // ---- Phase 1b: fill lower triangle by symmetry (64x64 bit transposes).
    // Items 0..27: off-diagonal pairs (bi,bj), bj<bi. Items 28..35: diagonal
    // blocks bi=bj=p-28, completed as x | transpose(x).
    for (int p = wave; p < 36; p += 16) {
        int bi, bj;
        if (p < 28) {
            bi = 1;
            while (bi * (bi + 1) / 2 <= p) ++bi;
            bj = p - bi * (bi - 1) / 2;
        } else {
            bi = p - 28; bj = bi;
        }
        unsigned long long x = bits[(bj << 6) + lane][bi];
        unsigned long long t = x;
        const unsigned long long M[6] = {
            0x5555555555555555ull, 0x3333333333333333ull,
            0x0f0f0f0f0f0f0f0full, 0x00ff00ff00ff00ffull,
            0x0000ffff0000ffffull, 0x00000000ffffffffull };
        #pragma unroll
        for (int s = 0; s < 6; ++s) {
            const int k = 1 << s;
            unsigned long long y = __shfl_xor((long long)t, k, 64);
            if ((lane & k) == 0) t = (t &  M[s]) | ((y &  M[s]) << k);
            else                 t = (t & ~M[s]) | ((y & ~M[s]) >> k);
        }
        if (p < 28) bits[(bi << 6) + lane][bj] = t;       // pure transpose
        else        bits[(bi << 6) + lane][bi] = x | t;   // symmetric completion
    }
    __syncthreads();

    // ---- Phase 2a: upper-tri edge list (j > r); j = 64m + L.
    for (int p = tid; p < NN * WORDS; p += 1024) {
        int r = p >> 3;
        int m = p & 7;
        unsigned long long w = bits[r][m];
        int base = m << 6;
        int sh = r - base + 1;  // keep bits L with base+L > r
        unsigned long long wm =
            (sh <= 0) ? w : (sh >= 64 ? 0ull : (w & (~0ull << sh)));
        int cnt = __popcll(wm);

        int x = cnt;
        #pragma unroll
        for (int off = 1; off < 64; off <<= 1) {
            int y = __shfl_up(x, off, 64);
            if (lane >= off) x += y;
        }
        int excl = x - cnt;
        int bs = 0;
        if (lane == 63) bs = atomicAdd(&ecnt, x);
        bs = __shfl(bs, 63, 64);

        int idx = bs + excl;
        while (wm) {
            int L = __builtin_ctzll(wm);
            wm &= wm - 1;
            int j = base + L;
            if (idx < ECAP) edges[idx] = ((unsigned)r << 10) | (unsigned)j;
            ++idx;
        }
    }
    __syncthreads();

    // ---- Phase 2b: edge-parallel intersection counts.
    const int ne = ecnt < ECAP ? ecnt : ECAP;
    for (int e = tid; e < ne; e += 1024) {
        unsigned ed = edges[e];
        int i = ed >> 10;
        int j = ed & 1023;
        int acc = 0;
        #pragma unroll
        for (int w = 0; w < WORDS; ++w)
            acc += __popcll(bits[i][w] & bits[j][w]);
        atomicAdd(&tri2[i], acc);
        atomicAdd(&tri2[j], acc);
    }
    __syncthreads();

    // ---- Phase 2c: clustering coeff + histogram.
    if (tid < NN) {
        int deg = 0;
        #pragma unroll
        for (int w = 0; w < WORDS; ++w) deg += __popcll(bits[tid][w]);
        float t2    = (float)tri2[tid];
        float degf  = (float)deg;
        float denom = degf * (degf - 1.0f);
        float c = denom > 0.0f ? t2 / denom : 0.0f;  // exact int/int in fp32
        int idx = (int)(c * 100.0f);                  // trunc == astype(int32)
        idx = idx < 0 ? 0 : (idx > BINS - 1 ? BINS - 1 : idx);
        atomicAdd(&histI[idx], 1);
    }
    __syncthreads();

    if (tid < BINS) hist[(size_t)gb * BINS + tid] = (float)histI[tid];
}

// ---------------- fused MMD kernel (partial + last-block final) -------------
__global__ __launch_bounds__(256) void k_mmd(
    const float* __restrict__ hist, float* __restrict__ partials,
    unsigned int* __restrict__ cnt, float* __restrict__ out)
{
    int p = blockIdx.x * 256 + threadIdx.x;
    int t   = p >> 14;          // 0:XX 1:YY 2:XY
    int rem = p & 16383;
    int i = rem >> 7;
    int j = rem & 127;
    const float4* x4;
    const float4* y4;
    float w;
    if (t == 0)      { x4 = (const float4*)(hist + (size_t)i * BINS);           y4 = (const float4*)(hist + (size_t)j * BINS);           w =  1.0f; }
    else if (t == 1) { x4 = (const float4*)(hist + (size_t)(BATCH + i) * BINS); y4 = (const float4*)(hist + (size_t)(BATCH + j) * BINS); w =  1.0f; }
    else             { x4 = (const float4*)(hist + (size_t)i * BINS);           y4 = (const float4*)(hist + (size_t)(BATCH + j) * BINS); w = -2.0f; }
    float sq = 0.0f;
    #pragma unroll
    for (int k = 0; k < BINS / 4; ++k) {
        float4 a = x4[k];
        float4 b = y4[k];
        float d0 = a.x - b.x, d1 = a.y - b.y, d2 = a.z - b.z, d3 = a.w - b.w;
        sq += d0 * d0 + d1 * d1 + d2 * d2 + d3 * d3;
    }
    float local = w * expf(-0.5f * sq);  // sigma=1

    __shared__ float red[256];
    __shared__ bool amLast;
    red[threadIdx.x] = local;
    __syncthreads();
    for (int s = 128; s >= 1; s >>= 1) {
        if (threadIdx.x < s) red[threadIdx.x] += red[threadIdx.x + s];
        __syncthreads();
    }
    if (threadIdx.x == 0) {
        partials[blockIdx.x] = red[0];
        __threadfence();                        // release partial (device scope)
        amLast = (atomicAdd(cnt, 1u) == 191u);  // device-scope counter
    }
    __syncthreads();
    if (amLast) {
        __threadfence();                        // acquire others' partials
        if (threadIdx.x < 64) {
            // byte-identical reduction order to R9's k_mmd_final
            float v = 0.0f;
            for (int q = threadIdx.x; q < 192; q += 64) v += partials[q];
            #pragma unroll
            for (int off = 32; off >= 1; off >>= 1) v += __shfl_xor(v, off, 64);
            if (threadIdx.x == 0) out[0] = v * (1.0f / (float)(BATCH * BATCH));
        }
    }
}

extern "C" void kernel_launch(void* const* d_in, const int* in_sizes, int n_in,
                              void* d_out, int out_size, void* d_ws, size_t ws_size,
                              hipStream_t stream) {
    const float* a1 = (const float*)d_in[0];
    const float* a2 = (const float*)d_in[1];
    float* out = (float*)d_out;

    const size_t hist_bytes = (size_t)2 * BATCH * BINS * 4;  // 102,400 B
    float* hist            = (float*)d_ws;
    float* partials        = (float*)((char*)d_ws + hist_bytes);          // 768 B
    unsigned int* mmd_cnt  = (unsigned int*)((char*)d_ws + hist_bytes + 1024);

    hipLaunchKernelGGL(k_cluster_hist, dim3(2 * BATCH), dim3(1024), 0, stream,
                       a1, a2, hist, mmd_cnt);
    hipLaunchKernelGGL(k_mmd, dim3(192), dim3(256), 0, stream,
                       hist, partials, mmd_cnt, out);
}